// Round 10
// baseline (9434.795 us; speedup 1.0000x reference)
//
#include <hip/hip_runtime.h>

// ============================================================================
// Transformer_72816875537065 v10: v9 + drain-free decoder barriers.
//  - Both decoder barriers only guard LDS data -> replace __syncthreads()
//    (which drains vmcnt(0), killing any prefetch: R7 evidence) with
//    s_waitcnt lgkmcnt(0) + raw s_barrier (guide §5 8-phase pattern).
//  - With loads now able to fly across barrier 1: restore v7's KnW4 float4
//    repack (32 coalesced loads vs 128 scalar) + 8-quad kn prefetch issued
//    right after the score FMAs (softmax+PV cover its latency) + q-cache.
//  - Encoder = v9 (transposed-V attn). No per-lane array > 32 floats.
// All fp32; threefry/gumbel/argmax bit-identical to passing R1-R9 code.
// ============================================================================

#define NEGINF (-__builtin_huge_valf())
#define TINYF 1.17549435e-38f

__device__ __forceinline__ unsigned rotl32(unsigned v, int r) {
  return (v << r) | (v >> (32 - r));
}

__device__ __forceinline__ void threefry2x32(unsigned k0, unsigned k1,
                                             unsigned& x0, unsigned& x1) {
  unsigned k2 = k0 ^ k1 ^ 0x1BD11BDAu;
  x0 += k0; x1 += k1;
#define TF_R(r) { x0 += x1; x1 = rotl32(x1, (r)); x1 ^= x0; }
  TF_R(13) TF_R(15) TF_R(26) TF_R(6)
  x0 += k1; x1 += k2 + 1u;
  TF_R(17) TF_R(29) TF_R(16) TF_R(24)
  x0 += k2; x1 += k0 + 2u;
  TF_R(13) TF_R(15) TF_R(26) TF_R(6)
  x0 += k0; x1 += k1 + 3u;
  TF_R(17) TF_R(29) TF_R(16) TF_R(24)
  x0 += k1; x1 += k2 + 4u;
  TF_R(13) TF_R(15) TF_R(26) TF_R(6)
  x0 += k2; x1 += k0 + 5u;
#undef TF_R
}

__device__ __forceinline__ float4 f4fma(float s, float4 v, float4 a) {
  a.x += s * v.x; a.y += s * v.y; a.z += s * v.z; a.w += s * v.w; return a;
}

// LDS-only barrier: does NOT drain vmcnt -> global loads stay in flight.
__device__ __forceinline__ void lds_barrier() {
  asm volatile("s_waitcnt lgkmcnt(0)" ::: "memory");
  __builtin_amdgcn_s_barrier();
  asm volatile("" ::: "memory");
}

// ---------------------------------------------------------------------------
__global__ __launch_bounds__(256) void k_embed(const float* __restrict__ P,
                                               const float* __restrict__ eW,
                                               const float* __restrict__ eb,
                                               float* __restrict__ X) {
  int idx = blockIdx.x * 256 + threadIdx.x;
  int row = idx >> 7, d = idx & 127;
  X[idx] = P[row * 2] * eW[d] + P[row * 2 + 1] * eW[128 + d] + eb[d];
}

// ---------------------------------------------------------------------------
// Small-M GEMM (M=64/1): C[M,128] = A[M,128] @ W[128,128]
// ---------------------------------------------------------------------------
__global__ __launch_bounds__(256) void k_gemm128(const float* __restrict__ A,
                                                 const float* __restrict__ W,
                                                 const float* __restrict__ R,
                                                 float* __restrict__ C, int M) {
  __shared__ float As[16][129];
  __shared__ float Ws[128][17];
  const int tx = threadIdx.x & 15, ty = threadIdx.x >> 4;
  const int row0 = blockIdx.x * 16, col0 = blockIdx.y * 16;
  for (int idx = threadIdx.x; idx < 2048; idx += 256) {
    int r = idx >> 7, k = idx & 127;
    As[r][k] = (row0 + r < M) ? A[(size_t)(row0 + r) * 128 + k] : 0.0f;
    int kk = idx >> 4, c = idx & 15;
    Ws[kk][c] = W[(size_t)kk * 128 + col0 + c];
  }
  __syncthreads();
  float acc = 0.0f;
#pragma unroll 8
  for (int k = 0; k < 128; ++k) acc += As[ty][k] * Ws[k][tx];
  const int row = row0 + ty, col = col0 + tx;
  if (row < M) {
    if (R) acc += R[(size_t)row * 128 + col];
    C[(size_t)row * 128 + col] = acc;
  }
}

// ---------------------------------------------------------------------------
// 64x64-tile fp32 GEMM, 256 threads, 4x4 outputs/thread, K in 128-chunks.
// ---------------------------------------------------------------------------
#define GEP_BIAS 1
#define GEP_RELU 2
#define GEP_ADDR 4
#define GEP_ACC  8
#define GEP_TST  16
#define GEP_WT   32

__global__ __launch_bounds__(256, 2) void k_gemm64(
    const float* __restrict__ A, int lda,
    const float* __restrict__ W, int ldw,
    const float* __restrict__ bias,
    const float* __restrict__ R,
    float* __restrict__ C, int ldc,
    int K, int flags) {
  __shared__ float AsT[128 * 68];
  __shared__ float Bs[128 * 68];
  const int t = threadIdx.x;
  const int tx = t & 15, ty = t >> 4;
  const int row0 = blockIdx.x * 64, col0 = blockIdx.y * 64;
  float4 acc[4];
  acc[0] = acc[1] = acc[2] = acc[3] = make_float4(0.f, 0.f, 0.f, 0.f);

  for (int K0 = 0; K0 < K; K0 += 128) {
    if (K0) __syncthreads();
#pragma unroll
    for (int j = 0; j < 8; ++j) {
      int idx = t + j * 256;
      int r = idx & 63, kq = idx >> 6;
      float4 v = *(const float4*)&A[(size_t)(row0 + r) * lda + K0 + kq * 4];
      AsT[(kq * 4 + 0) * 68 + r] = v.x;
      AsT[(kq * 4 + 1) * 68 + r] = v.y;
      AsT[(kq * 4 + 2) * 68 + r] = v.z;
      AsT[(kq * 4 + 3) * 68 + r] = v.w;
    }
    if (flags & GEP_WT) {
#pragma unroll
      for (int j = 0; j < 8; ++j) {
        int idx = t + j * 256;
        int cc = idx & 63, kq = idx >> 6;
        float4 v = *(const float4*)&W[(size_t)(col0 + cc) * ldw + K0 + kq * 4];
        Bs[(kq * 4 + 0) * 68 + cc] = v.x;
        Bs[(kq * 4 + 1) * 68 + cc] = v.y;
        Bs[(kq * 4 + 2) * 68 + cc] = v.z;
        Bs[(kq * 4 + 3) * 68 + cc] = v.w;
      }
    } else {
#pragma unroll
      for (int j = 0; j < 8; ++j) {
        int idx = t + j * 256;
        int c4 = idx & 15, k = idx >> 4;
        *(float4*)&Bs[k * 68 + c4 * 4] =
            *(const float4*)&W[(size_t)(K0 + k) * ldw + col0 + c4 * 4];
      }
    }
    __syncthreads();
#pragma unroll 8
    for (int k = 0; k < 128; ++k) {
      float4 av = *(const float4*)&AsT[k * 68 + ty * 4];
      float4 bv = *(const float4*)&Bs[k * 68 + tx * 4];
      acc[0] = f4fma(av.x, bv, acc[0]);
      acc[1] = f4fma(av.y, bv, acc[1]);
      acc[2] = f4fma(av.z, bv, acc[2]);
      acc[3] = f4fma(av.w, bv, acc[3]);
    }
  }

  if (flags & GEP_TST) {
    __syncthreads();
    float* CtT = AsT;
#pragma unroll
    for (int i2 = 0; i2 < 4; ++i2) {
      CtT[(tx * 4 + 0) * 68 + ty * 4 + i2] = ((const float*)&acc[i2])[0];
      CtT[(tx * 4 + 1) * 68 + ty * 4 + i2] = ((const float*)&acc[i2])[1];
      CtT[(tx * 4 + 2) * 68 + ty * 4 + i2] = ((const float*)&acc[i2])[2];
      CtT[(tx * 4 + 3) * 68 + ty * 4 + i2] = ((const float*)&acc[i2])[3];
    }
    __syncthreads();
    for (int j = 0; j < 16; ++j) {
      int idx = t + j * 256;
      int n = idx & 63, c = idx >> 6;
      int grow = row0 + n;
      C[(size_t)(grow >> 9) * 65536 + (size_t)(col0 + c) * 512 + (grow & 511)] =
          CtT[c * 68 + n];
    }
  } else {
#pragma unroll
    for (int i2 = 0; i2 < 4; ++i2) {
      const int row = row0 + ty * 4 + i2, col = col0 + tx * 4;
      float4 v = acc[i2];
      if (flags & GEP_BIAS) {
        float4 b4 = *(const float4*)&bias[col];
        v.x += b4.x; v.y += b4.y; v.z += b4.z; v.w += b4.w;
      }
      if (flags & GEP_RELU) {
        v.x = fmaxf(v.x, 0.f); v.y = fmaxf(v.y, 0.f);
        v.z = fmaxf(v.z, 0.f); v.w = fmaxf(v.w, 0.f);
      }
      if (flags & GEP_ADDR) {
        float4 r4 = *(const float4*)&R[(size_t)row * ldc + col];
        v.x += r4.x; v.y += r4.y; v.z += r4.z; v.w += r4.w;
      }
      if (flags & GEP_ACC) {
        float4 c4 = *(const float4*)&C[(size_t)row * ldc + col];
        v.x += c4.x; v.y += c4.y; v.z += c4.z; v.w += c4.w;
      }
      *(float4*)&C[(size_t)row * ldc + col] = v;
    }
  }
}

// ---------------------------------------------------------------------------
// Repack KnWT [b][k][n] -> KnW4 [b][k>>2][n][k&3] (float4-coalesced GEMV rows)
// ---------------------------------------------------------------------------
__global__ __launch_bounds__(256) void k_repack4(const float* __restrict__ in,
                                                 float* __restrict__ out) {
  int idx = blockIdx.x * 256 + threadIdx.x;     // 0 .. 64*32*512-1
  int n = idx & 511, q = (idx >> 9) & 31, b = idx >> 14;
  const float* ip = in + (size_t)b * 65536 + (size_t)(q * 4) * 512 + n;
  float4 v = make_float4(ip[0], ip[512], ip[1024], ip[1536]);
  *reinterpret_cast<float4*>(out + (size_t)b * 65536 + (size_t)q * 2048 + n * 4) = v;
}

// ---------------------------------------------------------------------------
// Encoder attention (v9): block = (b,h), 512 threads. K row t in regs; V
// transposed in LDS so the PV n-loop is float4 x float4.
// ---------------------------------------------------------------------------
__global__ __launch_bounds__(512, 2) void k_attn_enc(const float* __restrict__ Q,
                                                     const float* __restrict__ K,
                                                     const float* __restrict__ V,
                                                     float* __restrict__ O) {
  const int b = blockIdx.x >> 3, h = blockIdx.x & 7;
  const int t = threadIdx.x, l = t & 63, w = t >> 6;
  __shared__ float S[32][516];
  __shared__ float VsT[16][516];
  __shared__ float Qs[32][16];
  __shared__ float invr[32];
  const size_t base = (size_t)b * 512 * 128 + (size_t)h * 16;
  float4 k0, k1, k2, k3;
  {
    const float4* kr = reinterpret_cast<const float4*>(K + base + (size_t)t * 128);
    k0 = kr[0]; k1 = kr[1]; k2 = kr[2]; k3 = kr[3];
  }
  for (int idx = t; idx < 2048; idx += 512) {
    int n = idx >> 2, c = idx & 3;
    float4 v = reinterpret_cast<const float4*>(V + base + (size_t)n * 128)[c];
    VsT[4 * c + 0][n] = v.x;
    VsT[4 * c + 1][n] = v.y;
    VsT[4 * c + 2][n] = v.z;
    VsT[4 * c + 3][n] = v.w;
  }
  __syncthreads();
  for (int qt = 0; qt < 16; ++qt) {
    { int qr = t >> 4, d = t & 15;
      Qs[qr][d] = Q[base + (size_t)(qt * 32 + qr) * 128 + d]; }
    __syncthreads();
#pragma unroll 4
    for (int qi = 0; qi < 32; ++qi) {
      const float* qv = Qs[qi];
      float s = qv[0] * k0.x + qv[1] * k0.y + qv[2] * k0.z + qv[3] * k0.w
              + qv[4] * k1.x + qv[5] * k1.y + qv[6] * k1.z + qv[7] * k1.w
              + qv[8] * k2.x + qv[9] * k2.y + qv[10] * k2.z + qv[11] * k2.w
              + qv[12] * k3.x + qv[13] * k3.y + qv[14] * k3.z + qv[15] * k3.w;
      S[qi][t] = s * 0.25f;
    }
    __syncthreads();
    for (int r = 0; r < 4; ++r) {
      const int qi = w * 4 + r;
      float m = S[qi][l];
      for (int j = 1; j < 8; ++j) m = fmaxf(m, S[qi][l + 64 * j]);
      for (int o = 32; o; o >>= 1) m = fmaxf(m, __shfl_xor(m, o));
      float sum = 0.0f;
      for (int j = 0; j < 8; ++j) {
        float e = expf(S[qi][l + 64 * j] - m);
        S[qi][l + 64 * j] = e;
        sum += e;
      }
      for (int o = 32; o; o >>= 1) sum += __shfl_xor(sum, o);
      if (l == 0) invr[qi] = 1.0f / sum;
    }
    __syncthreads();
    {
      const int qi = t >> 4, d = t & 15;
      const float4* Srow = reinterpret_cast<const float4*>(&S[qi][0]);
      const float4* Vrow = reinterpret_cast<const float4*>(&VsT[d][0]);
      float4 a4 = make_float4(0.f, 0.f, 0.f, 0.f);
#pragma unroll 8
      for (int n4 = 0; n4 < 128; ++n4) {
        const float4 s4 = Srow[n4];
        const float4 v4 = Vrow[n4];
        a4.x += s4.x * v4.x; a4.y += s4.y * v4.y;
        a4.z += s4.z * v4.z; a4.w += s4.w * v4.w;
      }
      const float acc = (a4.x + a4.y) + (a4.z + a4.w);
      O[base + (size_t)(qt * 32 + qi) * 128 + d] = acc * invr[qi];
    }
  }
}

// ---------------------------------------------------------------------------
__global__ __launch_bounds__(256) void k_ln(const float* __restrict__ Y,
                                            const float* __restrict__ g,
                                            const float* __restrict__ bb,
                                            float* __restrict__ O, int M) {
  const int row = blockIdx.x * 4 + (threadIdx.x >> 6);
  const int l = threadIdx.x & 63;
  if (row >= M) return;
  const float* y = Y + (size_t)row * 128;
  float v0 = y[l], v1 = y[l + 64];
  float s = v0 + v1;
  for (int o = 32; o; o >>= 1) s += __shfl_xor(s, o);
  const float mu = s * (1.0f / 128.0f);
  float d0 = v0 - mu, d1 = v1 - mu;
  float q = d0 * d0 + d1 * d1;
  for (int o = 32; o; o >>= 1) q += __shfl_xor(q, o);
  const float sd = sqrtf(q * (1.0f / 128.0f) + 1e-6f);
  O[(size_t)row * 128 + l]      = d0 / sd * g[l] + bb[l];
  O[(size_t)row * 128 + l + 64] = d1 / sd * g[l + 64] + bb[l + 64];
}

// ---------------------------------------------------------------------------
__global__ __launch_bounds__(128) void k_mean(const float* __restrict__ X,
                                              float* __restrict__ NM) {
  const int b = blockIdx.x, d = threadIdx.x;
  float s = 0.0f;
  for (int n = 0; n < 512; ++n) s += X[((size_t)b * 512 + n) * 128 + d];
  NM[b * 128 + d] = s * (1.0f / 512.0f);
}

// ---------------------------------------------------------------------------
// Decoder v10: v6 structure + drain-free barriers + KnW4 prefetch + q-cache.
// 1 block/batch, 512 threads, wave w = head w.
// ---------------------------------------------------------------------------
__global__ __launch_bounds__(512, 2) void k_decoder(
    const float* __restrict__ Kt, const float* __restrict__ Vt,
    const float* __restrict__ KnW4,
    const float* __restrict__ QG, const float* __restrict__ QL,
    const float* __restrict__ QF, const float* __restrict__ QL0,
    const float* __restrict__ QF0,
    float* __restrict__ out_probs, float* __restrict__ out_act) {
  const int b = blockIdx.x, t = threadIdx.x;
  const int l = t & 63, w = t >> 6, h = w;

  __shared__ float att_s[128];
  __shared__ float pv[8][64 * 17];
  __shared__ float l_lds[512];
  __shared__ uint2 keys[512];
  __shared__ float redZ[8]; __shared__ int redI[8];
  __shared__ float redM[8]; __shared__ float redD[8];

  {
    unsigned x0 = 0u, x1 = (unsigned)t;
    threefry2x32(0u, 42u, x0, x1);
    keys[t] = make_uint2(x0, x1);
  }
  __syncthreads();

  const float4* KtB = reinterpret_cast<const float4*>(Kt + (size_t)b * 65536);
  const float4* VtB = reinterpret_cast<const float4*>(Vt + (size_t)b * 65536);
  const float4* kn4 = reinterpret_cast<const float4*>(KnW4 + (size_t)b * 65536);

  float4 mk0 = make_float4(0.f, 0.f, 0.f, 0.f);
  float4 mk1 = make_float4(0.f, 0.f, 0.f, 0.f);
  float emask = 0.0f;
  int ap = 0;

  // q-cache: QG row loaded once; QF[af] cached after step 0 (af fixed).
  float qg = 0.0f, qf_r = 0.0f;
  if (l < 16) qg = QG[b * 128 + h * 16 + l];

  for (int i = 0; i < 512; ++i) {
    // ---- (A) q for this head: (QG + QL[ap]) + QF[af]  (exact v6 order)
    float qval = 0.0f;
    if (l < 16) {
      const int c = h * 16 + l;
      const float ql_ = (i == 0) ? QL0[c] : QL[(size_t)ap * 128 + c];
      const float qf_ = (i == 0) ? QF0[c] : qf_r;
      qval = (qg + ql_) + qf_;
    }
    float q[16];
#pragma unroll
    for (int d = 0; d < 16; ++d) q[d] = __shfl(qval, d);
    // ---- (B) scores: stream Kt from L2
    float4 a0 = make_float4(0.f, 0.f, 0.f, 0.f);
    float4 a1 = make_float4(0.f, 0.f, 0.f, 0.f);
#pragma unroll
    for (int d = 0; d < 16; ++d) {
      a0 = f4fma(q[d], KtB[(h * 16 + d) * 128 + l], a0);
      a1 = f4fma(q[d], KtB[(h * 16 + d) * 128 + 64 + l], a1);
    }
    // ---- kn quads 0..7 prefetch: issued HERE so softmax+PV cover ~700cy
    // latency; the drain-free barrier below keeps them in flight.
    float4 kq[8];
#pragma unroll
    for (int q4 = 0; q4 < 8; ++q4) kq[q4] = kn4[q4 * 512 + t];
    // ---- PV group 0 prefetch (d 0..3): hides under softmax
    float4 va[4], vb[4];
#pragma unroll
    for (int u = 0; u < 4; ++u) {
      va[u] = VtB[(h * 16 + u) * 128 + l];
      vb[u] = VtB[(h * 16 + u) * 128 + 64 + l];
    }
    float4 s0, s1;
    s0.x = a0.x * 0.25f + mk0.x;  s0.y = a0.y * 0.25f + mk0.y;
    s0.z = a0.z * 0.25f + mk0.z;  s0.w = a0.w * 0.25f + mk0.w;
    s1.x = a1.x * 0.25f + mk1.x;  s1.y = a1.y * 0.25f + mk1.y;
    s1.z = a1.z * 0.25f + mk1.z;  s1.w = a1.w * 0.25f + mk1.w;
    float mh = fmaxf(fmaxf(fmaxf(s0.x, s0.y), fmaxf(s0.z, s0.w)),
                     fmaxf(fmaxf(s1.x, s1.y), fmaxf(s1.z, s1.w)));
    for (int o = 32; o; o >>= 1) mh = fmaxf(mh, __shfl_xor(mh, o));
    float4 e0, e1;
    e0.x = expf(s0.x - mh); e0.y = expf(s0.y - mh);
    e0.z = expf(s0.z - mh); e0.w = expf(s0.w - mh);
    e1.x = expf(s1.x - mh); e1.y = expf(s1.y - mh);
    e1.z = expf(s1.z - mh); e1.w = expf(s1.w - mh);
    float sden = ((e0.x + e0.y) + (e0.z + e0.w)) + ((e1.x + e1.y) + (e1.z + e1.w));
    for (int o = 32; o; o >>= 1) sden += __shfl_xor(sden, o);
    const float inv = 1.0f / sden;
    // ---- (C) PV: group 0 from prefetched regs, groups 1-3 load+fma
    float ps[16];
#pragma unroll
    for (int u = 0; u < 4; ++u) {
      ps[u] = e0.x * va[u].x + e0.y * va[u].y + e0.z * va[u].z + e0.w * va[u].w
            + e1.x * vb[u].x + e1.y * vb[u].y + e1.z * vb[u].z + e1.w * vb[u].w;
    }
#pragma unroll
    for (int dg = 1; dg < 4; ++dg) {
#pragma unroll
      for (int u = 0; u < 4; ++u) {
        va[u] = VtB[(h * 16 + dg * 4 + u) * 128 + l];
        vb[u] = VtB[(h * 16 + dg * 4 + u) * 128 + 64 + l];
      }
#pragma unroll
      for (int u = 0; u < 4; ++u) {
        ps[dg * 4 + u] = e0.x * va[u].x + e0.y * va[u].y + e0.z * va[u].z + e0.w * va[u].w
                       + e1.x * vb[u].x + e1.y * vb[u].y + e1.z * vb[u].z + e1.w * vb[u].w;
      }
    }
#pragma unroll
    for (int d = 0; d < 16; ++d) pv[w][l * 17 + d] = ps[d];
    asm volatile("s_waitcnt lgkmcnt(0)" ::: "memory");
    float sum = 0.0f;
#pragma unroll
    for (int j = 0; j < 16; ++j)
      sum += pv[w][((l >> 4) * 16 + j) * 17 + (l & 15)];
    sum += __shfl_xor(sum, 16);
    sum += __shfl_xor(sum, 32);
    if (l < 16) att_s[h * 16 + l] = sum * inv;
    lds_barrier();                                     // barrier 1 (LDS-only)
    // ---- (E) logits = att . KnW[n]; prefetched quads then streamed rest
    float lg, zv;
    {
      const float4* att4 = reinterpret_cast<const float4*>(att_s);
      float acc = 0.0f, acc2 = 0.0f;
#pragma unroll
      for (int q4 = 0; q4 < 8; ++q4) {
        const float4 av = att4[q4];
        const float4 kv = kq[q4];
        acc  += av.x * kv.x;  acc  += av.y * kv.y;
        acc2 += av.z * kv.z;  acc2 += av.w * kv.w;
      }
#pragma unroll 8
      for (int q4 = 8; q4 < 32; ++q4) {
        const float4 av = att4[q4];
        const float4 kv = kn4[q4 * 512 + t];
        acc  += av.x * kv.x;  acc  += av.y * kv.y;
        acc2 += av.z * kv.z;  acc2 += av.w * kv.w;
      }
      const float lraw = (acc + acc2) / 11.313708498984761f;  // / sqrt(128)
      lg = tanhf(lraw) * 10.0f + emask;
      l_lds[t] = lg;
      unsigned x0 = 0u, x1 = (unsigned)(b * 512 + t);
      const uint2 kk = keys[i];
      threefry2x32(kk.x, kk.y, x0, x1);
      const unsigned bits = x0 ^ x1;
      float f = __uint_as_float((bits >> 9) | 0x3f800000u) - 1.0f;
      f = f + TINYF;
      f = fmaxf(TINYF, f);
      zv = lg + (-logf(-logf(f)));
    }
    {
      float z = zv; int zi = t;
      float mm = lg;
      for (int o = 32; o; o >>= 1) {
        float oz = __shfl_xor(z, o); int oi = __shfl_xor(zi, o);
        if (oz > z || (oz == z && oi < zi)) { z = oz; zi = oi; }
        mm = fmaxf(mm, __shfl_xor(mm, o));
      }
      float e = expf(lg - mm);             // NaN if wave fully masked (guarded)
      for (int o = 32; o; o >>= 1) e += __shfl_xor(e, o);
      if (l == 0) { redZ[w] = z; redI[w] = zi; redM[w] = mm; redD[w] = e; }
    }
    lds_barrier();                                     // barrier 2 (LDS-only)
    // ---- every thread combines the 8 wave records (uniform result)
    float bz = redZ[0]; int a = redI[0]; float M = redM[0];
#pragma unroll
    for (int ww = 1; ww < 8; ++ww) {
      float oz = redZ[ww]; int oi = redI[ww];
      if (oz > bz || (oz == bz && oi < a)) { bz = oz; a = oi; }
      M = fmaxf(M, redM[ww]);
    }
    if (t == 0) {
      float den = 0.0f;
#pragma unroll
      for (int ww = 0; ww < 8; ++ww) {
        float mw = redM[ww];
        if (mw != NEGINF) den += redD[ww] * expf(mw - M);
      }
      out_probs[i * 64 + b] = expf(l_lds[a] - M) / den;
      out_act[i * 64 + b] = (float)a;
    }
    ap = a;
    if (i == 0 && l < 16) qf_r = QF[(size_t)a * 128 + h * 16 + l];
    const int n0 = l << 2;
    mk0.x = (a == n0)       ? NEGINF : mk0.x;
    mk0.y = (a == n0 + 1)   ? NEGINF : mk0.y;
    mk0.z = (a == n0 + 2)   ? NEGINF : mk0.z;
    mk0.w = (a == n0 + 3)   ? NEGINF : mk0.w;
    mk1.x = (a == 256 + n0)     ? NEGINF : mk1.x;
    mk1.y = (a == 256 + n0 + 1) ? NEGINF : mk1.y;
    mk1.z = (a == 256 + n0 + 2) ? NEGINF : mk1.z;
    mk1.w = (a == 256 + n0 + 3) ? NEGINF : mk1.w;
    emask = (a == t) ? NEGINF : emask;
  }
}

// ===========================================================================
extern "C" void kernel_launch(void* const* d_in, const int* in_sizes, int n_in,
                              void* d_out, int out_size, void* d_ws, size_t ws_size,
                              hipStream_t stream) {
  const float* problems = (const float*)d_in[0];
  const float* embed_W  = (const float*)d_in[1];
  const float* embed_b  = (const float*)d_in[2];
  const float* enc_Wq   = (const float*)d_in[3];
  const float* enc_Wk   = (const float*)d_in[4];
  const float* enc_Wv   = (const float*)d_in[5];
  const float* enc_Wo   = (const float*)d_in[6];
  const float* ln1g     = (const float*)d_in[7];
  const float* ln1b     = (const float*)d_in[8];
  const float* ffW1     = (const float*)d_in[9];
  const float* ffb1     = (const float*)d_in[10];
  const float* ffW2     = (const float*)d_in[11];
  const float* ffb2     = (const float*)d_in[12];
  const float* ln2g     = (const float*)d_in[13];
  const float* ln2b     = (const float*)d_in[14];
  const float* graph_W  = (const float*)d_in[15];
  const float* node_W   = (const float*)d_in[16];
  const float* dec_Wq   = (const float*)d_in[17];
  const float* dec_Wk   = (const float*)d_in[18];
  const float* dec_Wv   = (const float*)d_in[19];
  const float* dec_Wo   = (const float*)d_in[20];
  const float* W_v_f    = (const float*)d_in[21];
  const float* W_v_l    = (const float*)d_in[22];

  float* ws = (float*)d_ws;
  const size_t SZ = (size_t)64 * 512 * 128;      // 16 MB each
  float* X  = ws;
  float* Y  = ws + SZ;
  float* Qb = ws + 2 * SZ;
  float* Kb = ws + 3 * SZ;
  float* Vb = ws + 4 * SZ;
  float* NM = ws + 5 * SZ;
  float* GC = NM + 64 * 128;

  float* QG  = Y;
  float* QL  = Y + 8192;
  float* QF  = Y + 8192 + 65536;
  float* QL0 = Y + 8192 + 131072;
  float* QF0 = QL0 + 128;

  float* out       = (float*)d_out;
  float* out_probs = out;
  float* out_act   = out + 512 * 64;

  k_embed<<<16384, 256, 0, stream>>>(problems, embed_W, embed_b, X);

  for (int i = 0; i < 3; ++i) {
    const float* Wqi = enc_Wq + (size_t)i * 16384;
    const float* Wki = enc_Wk + (size_t)i * 16384;
    const float* Wvi = enc_Wv + (size_t)i * 16384;
    const float* Woi = enc_Wo + (size_t)i * 16384;
    k_gemm64<<<dim3(512, 2), 256, 0, stream>>>(X, 128, Wqi, 128, nullptr, nullptr, Qb, 128, 128, 0);
    k_gemm64<<<dim3(512, 2), 256, 0, stream>>>(X, 128, Wki, 128, nullptr, nullptr, Kb, 128, 128, 0);
    k_gemm64<<<dim3(512, 2), 256, 0, stream>>>(X, 128, Wvi, 128, nullptr, nullptr, Vb, 128, 128, 0);
    k_attn_enc<<<512, 512, 0, stream>>>(Qb, Kb, Vb, Y);
    k_gemm64<<<dim3(512, 2), 256, 0, stream>>>(Y, 128, Woi, 128, nullptr, X, Qb, 128, 128, GEP_ADDR);
    k_ln<<<8192, 256, 0, stream>>>(Qb, ln1g + i * 128, ln1b + i * 128, X, 32768);
    float* H = Kb;
    for (int half = 0; half < 2; ++half) {
      k_gemm64<<<dim3(512, 4), 256, 0, stream>>>(
          X, 128, ffW1 + (size_t)i * 65536 + half * 256, 512,
          ffb1 + i * 512 + half * 256, nullptr, H, 256, 128, GEP_BIAS | GEP_RELU);
      k_gemm64<<<dim3(512, 2), 256, 0, stream>>>(
          H, 256, ffW2 + (size_t)i * 65536 + (size_t)half * 32768, 128,
          ffb2 + i * 128, X, Y, 128, 256,
          half == 0 ? (GEP_BIAS | GEP_ADDR) : GEP_ACC);
    }
    k_ln<<<8192, 256, 0, stream>>>(Y, ln2g + i * 128, ln2b + i * 128, X, 32768);
  }

  k_mean<<<64, 128, 0, stream>>>(X, NM);
  k_gemm128<<<dim3(4, 8), 256, 0, stream>>>(NM, graph_W, nullptr, GC, 64);
  k_gemm128<<<dim3(4, 8), 256, 0, stream>>>(GC, dec_Wq, nullptr, QG, 64);
  k_gemm64<<<dim3(8, 2), 256, 0, stream>>>(X, 128, dec_Wq + 16384, 128, nullptr, nullptr, QL, 128, 128, 0);
  k_gemm64<<<dim3(8, 2), 256, 0, stream>>>(X, 128, dec_Wq + 32768, 128, nullptr, nullptr, QF, 128, 128, 0);
  k_gemm128<<<dim3(1, 8), 256, 0, stream>>>(W_v_l, dec_Wq + 16384, nullptr, QL0, 1);
  k_gemm128<<<dim3(1, 8), 256, 0, stream>>>(W_v_f, dec_Wq + 32768, nullptr, QF0, 1);
  k_gemm64<<<dim3(512, 2), 256, 0, stream>>>(X, 128, dec_Wk, 128, nullptr, nullptr, Qb, 128, 128, GEP_TST);   // Kt
  k_gemm64<<<dim3(512, 2), 256, 0, stream>>>(X, 128, dec_Wv, 128, nullptr, nullptr, Kb, 128, 128, GEP_TST);   // Vt
  k_gemm64<<<dim3(512, 2), 256, 0, stream>>>(X, 128, node_W, 128, nullptr, nullptr, Vb, 128, 128, 0);         // kn
  k_gemm64<<<dim3(512, 2), 256, 0, stream>>>(Vb, 128, dec_Wo, 128, nullptr, nullptr, X, 128, 128,
                                             GEP_WT | GEP_TST);                                               // KnWT
  k_repack4<<<4096, 256, 0, stream>>>(X, Vb);                                                                 // KnW4

  k_decoder<<<64, 512, 0, stream>>>(Qb, Kb, Vb, QG, QL, QF, QL0, QF0,
                                    out_probs, out_act);
}

// Round 11
// 8198.868 us; speedup vs baseline: 1.1507x; 1.1507x over previous
//
#include <hip/hip_runtime.h>

// ============================================================================
// Transformer_72816875537065 v11: best-measured configuration restored.
//  - decoder: v6 exactly (5.88 ms measured; R7/R8/R10 alternatives all lost).
//  - encoder: v9 (transposed-V attn) + QKV GEMMs fused into one dispatch
//    (blockIdx.z selects W/output; per-z math bit-identical).
// Design-space conclusions baked in: no per-lane array > 32 floats (R3-R5
// spills); no prefetch across barriers (R7/R10); no cross-block sync (R8);
// kn GEMV stays scalar-streamed (R7/R10: float4 repack+prefetch regress).
// All fp32; threefry/gumbel/argmax bit-identical to passing R1-R10 code.
// ============================================================================

#define NEGINF (-__builtin_huge_valf())
#define TINYF 1.17549435e-38f

__device__ __forceinline__ unsigned rotl32(unsigned v, int r) {
  return (v << r) | (v >> (32 - r));
}

__device__ __forceinline__ void threefry2x32(unsigned k0, unsigned k1,
                                             unsigned& x0, unsigned& x1) {
  unsigned k2 = k0 ^ k1 ^ 0x1BD11BDAu;
  x0 += k0; x1 += k1;
#define TF_R(r) { x0 += x1; x1 = rotl32(x1, (r)); x1 ^= x0; }
  TF_R(13) TF_R(15) TF_R(26) TF_R(6)
  x0 += k1; x1 += k2 + 1u;
  TF_R(17) TF_R(29) TF_R(16) TF_R(24)
  x0 += k2; x1 += k0 + 2u;
  TF_R(13) TF_R(15) TF_R(26) TF_R(6)
  x0 += k0; x1 += k1 + 3u;
  TF_R(17) TF_R(29) TF_R(16) TF_R(24)
  x0 += k1; x1 += k2 + 4u;
  TF_R(13) TF_R(15) TF_R(26) TF_R(6)
  x0 += k2; x1 += k0 + 5u;
#undef TF_R
}

__device__ __forceinline__ float4 f4fma(float s, float4 v, float4 a) {
  a.x += s * v.x; a.y += s * v.y; a.z += s * v.z; a.w += s * v.w; return a;
}

// ---------------------------------------------------------------------------
__global__ __launch_bounds__(256) void k_embed(const float* __restrict__ P,
                                               const float* __restrict__ eW,
                                               const float* __restrict__ eb,
                                               float* __restrict__ X) {
  int idx = blockIdx.x * 256 + threadIdx.x;
  int row = idx >> 7, d = idx & 127;
  X[idx] = P[row * 2] * eW[d] + P[row * 2 + 1] * eW[128 + d] + eb[d];
}

// ---------------------------------------------------------------------------
// Small-M GEMM (M=64/1): C[M,128] = A[M,128] @ W[128,128]
// ---------------------------------------------------------------------------
__global__ __launch_bounds__(256) void k_gemm128(const float* __restrict__ A,
                                                 const float* __restrict__ W,
                                                 const float* __restrict__ R,
                                                 float* __restrict__ C, int M) {
  __shared__ float As[16][129];
  __shared__ float Ws[128][17];
  const int tx = threadIdx.x & 15, ty = threadIdx.x >> 4;
  const int row0 = blockIdx.x * 16, col0 = blockIdx.y * 16;
  for (int idx = threadIdx.x; idx < 2048; idx += 256) {
    int r = idx >> 7, k = idx & 127;
    As[r][k] = (row0 + r < M) ? A[(size_t)(row0 + r) * 128 + k] : 0.0f;
    int kk = idx >> 4, c = idx & 15;
    Ws[kk][c] = W[(size_t)kk * 128 + col0 + c];
  }
  __syncthreads();
  float acc = 0.0f;
#pragma unroll 8
  for (int k = 0; k < 128; ++k) acc += As[ty][k] * Ws[k][tx];
  const int row = row0 + ty, col = col0 + tx;
  if (row < M) {
    if (R) acc += R[(size_t)row * 128 + col];
    C[(size_t)row * 128 + col] = acc;
  }
}

// ---------------------------------------------------------------------------
// 64x64-tile fp32 GEMM, 256 threads, 4x4 outputs/thread, K in 128-chunks.
// ---------------------------------------------------------------------------
#define GEP_BIAS 1
#define GEP_RELU 2
#define GEP_ADDR 4
#define GEP_ACC  8
#define GEP_TST  16
#define GEP_WT   32

__global__ __launch_bounds__(256, 2) void k_gemm64(
    const float* __restrict__ A, int lda,
    const float* __restrict__ W, int ldw,
    const float* __restrict__ bias,
    const float* __restrict__ R,
    float* __restrict__ C, int ldc,
    int K, int flags) {
  __shared__ float AsT[128 * 68];
  __shared__ float Bs[128 * 68];
  const int t = threadIdx.x;
  const int tx = t & 15, ty = t >> 4;
  const int row0 = blockIdx.x * 64, col0 = blockIdx.y * 64;
  float4 acc[4];
  acc[0] = acc[1] = acc[2] = acc[3] = make_float4(0.f, 0.f, 0.f, 0.f);

  for (int K0 = 0; K0 < K; K0 += 128) {
    if (K0) __syncthreads();
#pragma unroll
    for (int j = 0; j < 8; ++j) {
      int idx = t + j * 256;
      int r = idx & 63, kq = idx >> 6;
      float4 v = *(const float4*)&A[(size_t)(row0 + r) * lda + K0 + kq * 4];
      AsT[(kq * 4 + 0) * 68 + r] = v.x;
      AsT[(kq * 4 + 1) * 68 + r] = v.y;
      AsT[(kq * 4 + 2) * 68 + r] = v.z;
      AsT[(kq * 4 + 3) * 68 + r] = v.w;
    }
    if (flags & GEP_WT) {
#pragma unroll
      for (int j = 0; j < 8; ++j) {
        int idx = t + j * 256;
        int cc = idx & 63, kq = idx >> 6;
        float4 v = *(const float4*)&W[(size_t)(col0 + cc) * ldw + K0 + kq * 4];
        Bs[(kq * 4 + 0) * 68 + cc] = v.x;
        Bs[(kq * 4 + 1) * 68 + cc] = v.y;
        Bs[(kq * 4 + 2) * 68 + cc] = v.z;
        Bs[(kq * 4 + 3) * 68 + cc] = v.w;
      }
    } else {
#pragma unroll
      for (int j = 0; j < 8; ++j) {
        int idx = t + j * 256;
        int c4 = idx & 15, k = idx >> 4;
        *(float4*)&Bs[k * 68 + c4 * 4] =
            *(const float4*)&W[(size_t)(K0 + k) * ldw + col0 + c4 * 4];
      }
    }
    __syncthreads();
#pragma unroll 8
    for (int k = 0; k < 128; ++k) {
      float4 av = *(const float4*)&AsT[k * 68 + ty * 4];
      float4 bv = *(const float4*)&Bs[k * 68 + tx * 4];
      acc[0] = f4fma(av.x, bv, acc[0]);
      acc[1] = f4fma(av.y, bv, acc[1]);
      acc[2] = f4fma(av.z, bv, acc[2]);
      acc[3] = f4fma(av.w, bv, acc[3]);
    }
  }

  if (flags & GEP_TST) {
    __syncthreads();
    float* CtT = AsT;
#pragma unroll
    for (int i2 = 0; i2 < 4; ++i2) {
      CtT[(tx * 4 + 0) * 68 + ty * 4 + i2] = ((const float*)&acc[i2])[0];
      CtT[(tx * 4 + 1) * 68 + ty * 4 + i2] = ((const float*)&acc[i2])[1];
      CtT[(tx * 4 + 2) * 68 + ty * 4 + i2] = ((const float*)&acc[i2])[2];
      CtT[(tx * 4 + 3) * 68 + ty * 4 + i2] = ((const float*)&acc[i2])[3];
    }
    __syncthreads();
    for (int j = 0; j < 16; ++j) {
      int idx = t + j * 256;
      int n = idx & 63, c = idx >> 6;
      int grow = row0 + n;
      C[(size_t)(grow >> 9) * 65536 + (size_t)(col0 + c) * 512 + (grow & 511)] =
          CtT[c * 68 + n];
    }
  } else {
#pragma unroll
    for (int i2 = 0; i2 < 4; ++i2) {
      const int row = row0 + ty * 4 + i2, col = col0 + tx * 4;
      float4 v = acc[i2];
      if (flags & GEP_BIAS) {
        float4 b4 = *(const float4*)&bias[col];
        v.x += b4.x; v.y += b4.y; v.z += b4.z; v.w += b4.w;
      }
      if (flags & GEP_RELU) {
        v.x = fmaxf(v.x, 0.f); v.y = fmaxf(v.y, 0.f);
        v.z = fmaxf(v.z, 0.f); v.w = fmaxf(v.w, 0.f);
      }
      if (flags & GEP_ADDR) {
        float4 r4 = *(const float4*)&R[(size_t)row * ldc + col];
        v.x += r4.x; v.y += r4.y; v.z += r4.z; v.w += r4.w;
      }
      if (flags & GEP_ACC) {
        float4 c4 = *(const float4*)&C[(size_t)row * ldc + col];
        v.x += c4.x; v.y += c4.y; v.z += c4.z; v.w += c4.w;
      }
      *(float4*)&C[(size_t)row * ldc + col] = v;
    }
  }
}

// ---------------------------------------------------------------------------
// Fused Q/K/V projection: one dispatch, blockIdx.z selects W and output.
// Per-z math is bit-identical to three k_gemm64 flags=0 launches.
// ---------------------------------------------------------------------------
__global__ __launch_bounds__(256, 2) void k_gemm64_qkv(
    const float* __restrict__ A,
    const float* __restrict__ Wq, const float* __restrict__ Wk,
    const float* __restrict__ Wv,
    float* __restrict__ Cq, float* __restrict__ Ck, float* __restrict__ Cv) {
  const float* __restrict__ W = (blockIdx.z == 0) ? Wq : (blockIdx.z == 1) ? Wk : Wv;
  float* __restrict__ C = (blockIdx.z == 0) ? Cq : (blockIdx.z == 1) ? Ck : Cv;
  __shared__ float AsT[128 * 68];
  __shared__ float Bs[128 * 68];
  const int t = threadIdx.x;
  const int tx = t & 15, ty = t >> 4;
  const int row0 = blockIdx.x * 64, col0 = blockIdx.y * 64;
  float4 acc[4];
  acc[0] = acc[1] = acc[2] = acc[3] = make_float4(0.f, 0.f, 0.f, 0.f);
#pragma unroll
  for (int j = 0; j < 8; ++j) {
    int idx = t + j * 256;
    int r = idx & 63, kq = idx >> 6;
    float4 v = *(const float4*)&A[(size_t)(row0 + r) * 128 + kq * 4];
    AsT[(kq * 4 + 0) * 68 + r] = v.x;
    AsT[(kq * 4 + 1) * 68 + r] = v.y;
    AsT[(kq * 4 + 2) * 68 + r] = v.z;
    AsT[(kq * 4 + 3) * 68 + r] = v.w;
  }
#pragma unroll
  for (int j = 0; j < 8; ++j) {
    int idx = t + j * 256;
    int c4 = idx & 15, k = idx >> 4;
    *(float4*)&Bs[k * 68 + c4 * 4] =
        *(const float4*)&W[(size_t)k * 128 + col0 + c4 * 4];
  }
  __syncthreads();
#pragma unroll 8
  for (int k = 0; k < 128; ++k) {
    float4 av = *(const float4*)&AsT[k * 68 + ty * 4];
    float4 bv = *(const float4*)&Bs[k * 68 + tx * 4];
    acc[0] = f4fma(av.x, bv, acc[0]);
    acc[1] = f4fma(av.y, bv, acc[1]);
    acc[2] = f4fma(av.z, bv, acc[2]);
    acc[3] = f4fma(av.w, bv, acc[3]);
  }
#pragma unroll
  for (int i2 = 0; i2 < 4; ++i2) {
    const int row = row0 + ty * 4 + i2, col = col0 + tx * 4;
    *(float4*)&C[(size_t)row * 128 + col] = acc[i2];
  }
}

// ---------------------------------------------------------------------------
// Encoder attention (v9): block = (b,h), 512 threads. K row t in regs; V
// transposed in LDS so the PV n-loop is float4 x float4.
// ---------------------------------------------------------------------------
__global__ __launch_bounds__(512, 2) void k_attn_enc(const float* __restrict__ Q,
                                                     const float* __restrict__ K,
                                                     const float* __restrict__ V,
                                                     float* __restrict__ O) {
  const int b = blockIdx.x >> 3, h = blockIdx.x & 7;
  const int t = threadIdx.x, l = t & 63, w = t >> 6;
  __shared__ float S[32][516];
  __shared__ float VsT[16][516];
  __shared__ float Qs[32][16];
  __shared__ float invr[32];
  const size_t base = (size_t)b * 512 * 128 + (size_t)h * 16;
  float4 k0, k1, k2, k3;
  {
    const float4* kr = reinterpret_cast<const float4*>(K + base + (size_t)t * 128);
    k0 = kr[0]; k1 = kr[1]; k2 = kr[2]; k3 = kr[3];
  }
  for (int idx = t; idx < 2048; idx += 512) {
    int n = idx >> 2, c = idx & 3;
    float4 v = reinterpret_cast<const float4*>(V + base + (size_t)n * 128)[c];
    VsT[4 * c + 0][n] = v.x;
    VsT[4 * c + 1][n] = v.y;
    VsT[4 * c + 2][n] = v.z;
    VsT[4 * c + 3][n] = v.w;
  }
  __syncthreads();
  for (int qt = 0; qt < 16; ++qt) {
    { int qr = t >> 4, d = t & 15;
      Qs[qr][d] = Q[base + (size_t)(qt * 32 + qr) * 128 + d]; }
    __syncthreads();
#pragma unroll 4
    for (int qi = 0; qi < 32; ++qi) {
      const float* qv = Qs[qi];
      float s = qv[0] * k0.x + qv[1] * k0.y + qv[2] * k0.z + qv[3] * k0.w
              + qv[4] * k1.x + qv[5] * k1.y + qv[6] * k1.z + qv[7] * k1.w
              + qv[8] * k2.x + qv[9] * k2.y + qv[10] * k2.z + qv[11] * k2.w
              + qv[12] * k3.x + qv[13] * k3.y + qv[14] * k3.z + qv[15] * k3.w;
      S[qi][t] = s * 0.25f;
    }
    __syncthreads();
    for (int r = 0; r < 4; ++r) {
      const int qi = w * 4 + r;
      float m = S[qi][l];
      for (int j = 1; j < 8; ++j) m = fmaxf(m, S[qi][l + 64 * j]);
      for (int o = 32; o; o >>= 1) m = fmaxf(m, __shfl_xor(m, o));
      float sum = 0.0f;
      for (int j = 0; j < 8; ++j) {
        float e = expf(S[qi][l + 64 * j] - m);
        S[qi][l + 64 * j] = e;
        sum += e;
      }
      for (int o = 32; o; o >>= 1) sum += __shfl_xor(sum, o);
      if (l == 0) invr[qi] = 1.0f / sum;
    }
    __syncthreads();
    {
      const int qi = t >> 4, d = t & 15;
      const float4* Srow = reinterpret_cast<const float4*>(&S[qi][0]);
      const float4* Vrow = reinterpret_cast<const float4*>(&VsT[d][0]);
      float4 a4 = make_float4(0.f, 0.f, 0.f, 0.f);
#pragma unroll 8
      for (int n4 = 0; n4 < 128; ++n4) {
        const float4 s4 = Srow[n4];
        const float4 v4 = Vrow[n4];
        a4.x += s4.x * v4.x; a4.y += s4.y * v4.y;
        a4.z += s4.z * v4.z; a4.w += s4.w * v4.w;
      }
      const float acc = (a4.x + a4.y) + (a4.z + a4.w);
      O[base + (size_t)(qt * 32 + qi) * 128 + d] = acc * invr[qi];
    }
  }
}

// ---------------------------------------------------------------------------
__global__ __launch_bounds__(256) void k_ln(const float* __restrict__ Y,
                                            const float* __restrict__ g,
                                            const float* __restrict__ bb,
                                            float* __restrict__ O, int M) {
  const int row = blockIdx.x * 4 + (threadIdx.x >> 6);
  const int l = threadIdx.x & 63;
  if (row >= M) return;
  const float* y = Y + (size_t)row * 128;
  float v0 = y[l], v1 = y[l + 64];
  float s = v0 + v1;
  for (int o = 32; o; o >>= 1) s += __shfl_xor(s, o);
  const float mu = s * (1.0f / 128.0f);
  float d0 = v0 - mu, d1 = v1 - mu;
  float q = d0 * d0 + d1 * d1;
  for (int o = 32; o; o >>= 1) q += __shfl_xor(q, o);
  const float sd = sqrtf(q * (1.0f / 128.0f) + 1e-6f);
  O[(size_t)row * 128 + l]      = d0 / sd * g[l] + bb[l];
  O[(size_t)row * 128 + l + 64] = d1 / sd * g[l + 64] + bb[l + 64];
}

// ---------------------------------------------------------------------------
__global__ __launch_bounds__(128) void k_mean(const float* __restrict__ X,
                                              float* __restrict__ NM) {
  const int b = blockIdx.x, d = threadIdx.x;
  float s = 0.0f;
  for (int n = 0; n < 512; ++n) s += X[((size_t)b * 512 + n) * 128 + d];
  NM[b * 128 + d] = s * (1.0f / 512.0f);
}

// ---------------------------------------------------------------------------
// Decoder (v6, proven best): 1 block/batch, 512 threads, wave w = head w.
// ---------------------------------------------------------------------------
__global__ __launch_bounds__(512, 2) void k_decoder(
    const float* __restrict__ Kt, const float* __restrict__ Vt,
    const float* __restrict__ KnWT,
    const float* __restrict__ QG, const float* __restrict__ QL,
    const float* __restrict__ QF, const float* __restrict__ QL0,
    const float* __restrict__ QF0,
    float* __restrict__ out_probs, float* __restrict__ out_act) {
  const int b = blockIdx.x, t = threadIdx.x;
  const int l = t & 63, w = t >> 6, h = w;

  __shared__ float att_s[128];
  __shared__ float pv[8][64 * 17];
  __shared__ float l_lds[512];
  __shared__ uint2 keys[512];
  __shared__ float redZ[8]; __shared__ int redI[8];
  __shared__ float redM[8]; __shared__ float redD[8];

  {
    unsigned x0 = 0u, x1 = (unsigned)t;
    threefry2x32(0u, 42u, x0, x1);
    keys[t] = make_uint2(x0, x1);
  }
  __syncthreads();

  const float4* KtB = reinterpret_cast<const float4*>(Kt + (size_t)b * 65536);
  const float4* VtB = reinterpret_cast<const float4*>(Vt + (size_t)b * 65536);
  const float*  knB = KnWT + (size_t)b * 65536;

  float4 mk0 = make_float4(0.f, 0.f, 0.f, 0.f);
  float4 mk1 = make_float4(0.f, 0.f, 0.f, 0.f);
  float emask = 0.0f;
  int ap = 0, af = 0;

  for (int i = 0; i < 512; ++i) {
    // ---- (A) q for this head
    float qval = 0.0f;
    if (l < 16) {
      const int c = h * 16 + l;
      float s_ = QG[b * 128 + c];
      s_ += (i == 0) ? QL0[c] : QL[(size_t)ap * 128 + c];
      s_ += (i == 0) ? QF0[c] : QF[(size_t)af * 128 + c];
      qval = s_;
    }
    float q[16];
#pragma unroll
    for (int d = 0; d < 16; ++d) q[d] = __shfl(qval, d);
    // ---- (B) scores: stream Kt from L2 (no arrays)
    float4 a0 = make_float4(0.f, 0.f, 0.f, 0.f);
    float4 a1 = make_float4(0.f, 0.f, 0.f, 0.f);
#pragma unroll
    for (int d = 0; d < 16; ++d) {
      a0 = f4fma(q[d], KtB[(h * 16 + d) * 128 + l], a0);
      a1 = f4fma(q[d], KtB[(h * 16 + d) * 128 + 64 + l], a1);
    }
    // ---- PV group 0 prefetch (d 0..3): static addresses, hides under softmax
    float4 va[4], vb[4];
#pragma unroll
    for (int u = 0; u < 4; ++u) {
      va[u] = VtB[(h * 16 + u) * 128 + l];
      vb[u] = VtB[(h * 16 + u) * 128 + 64 + l];
    }
    float4 s0, s1;
    s0.x = a0.x * 0.25f + mk0.x;  s0.y = a0.y * 0.25f + mk0.y;
    s0.z = a0.z * 0.25f + mk0.z;  s0.w = a0.w * 0.25f + mk0.w;
    s1.x = a1.x * 0.25f + mk1.x;  s1.y = a1.y * 0.25f + mk1.y;
    s1.z = a1.z * 0.25f + mk1.z;  s1.w = a1.w * 0.25f + mk1.w;
    float mh = fmaxf(fmaxf(fmaxf(s0.x, s0.y), fmaxf(s0.z, s0.w)),
                     fmaxf(fmaxf(s1.x, s1.y), fmaxf(s1.z, s1.w)));
    for (int o = 32; o; o >>= 1) mh = fmaxf(mh, __shfl_xor(mh, o));
    float4 e0, e1;
    e0.x = expf(s0.x - mh); e0.y = expf(s0.y - mh);
    e0.z = expf(s0.z - mh); e0.w = expf(s0.w - mh);
    e1.x = expf(s1.x - mh); e1.y = expf(s1.y - mh);
    e1.z = expf(s1.z - mh); e1.w = expf(s1.w - mh);
    float sden = ((e0.x + e0.y) + (e0.z + e0.w)) + ((e1.x + e1.y) + (e1.z + e1.w));
    for (int o = 32; o; o >>= 1) sden += __shfl_xor(sden, o);
    const float inv = 1.0f / sden;
    // ---- (C) PV: group 0 from prefetched regs, groups 1-3 load+fma
    float ps[16];
#pragma unroll
    for (int u = 0; u < 4; ++u) {
      ps[u] = e0.x * va[u].x + e0.y * va[u].y + e0.z * va[u].z + e0.w * va[u].w
            + e1.x * vb[u].x + e1.y * vb[u].y + e1.z * vb[u].z + e1.w * vb[u].w;
    }
#pragma unroll
    for (int dg = 1; dg < 4; ++dg) {
#pragma unroll
      for (int u = 0; u < 4; ++u) {
        va[u] = VtB[(h * 16 + dg * 4 + u) * 128 + l];
        vb[u] = VtB[(h * 16 + dg * 4 + u) * 128 + 64 + l];
      }
#pragma unroll
      for (int u = 0; u < 4; ++u) {
        ps[dg * 4 + u] = e0.x * va[u].x + e0.y * va[u].y + e0.z * va[u].z + e0.w * va[u].w
                       + e1.x * vb[u].x + e1.y * vb[u].y + e1.z * vb[u].z + e1.w * vb[u].w;
      }
    }
#pragma unroll
    for (int d = 0; d < 16; ++d) pv[w][l * 17 + d] = ps[d];
    asm volatile("s_waitcnt lgkmcnt(0)" ::: "memory");
    float sum = 0.0f;
#pragma unroll
    for (int j = 0; j < 16; ++j)
      sum += pv[w][((l >> 4) * 16 + j) * 17 + (l & 15)];
    sum += __shfl_xor(sum, 16);
    sum += __shfl_xor(sum, 32);
    if (l < 16) att_s[h * 16 + l] = sum * inv;
    __syncthreads();                                   // barrier 1
    // ---- (E) logits = att . KnW[n], direct stream
    float lg, zv;
    {
      const float4* att4 = reinterpret_cast<const float4*>(att_s);
      const float* kc = knB + t;
      float acc = 0.0f, acc2 = 0.0f;
#pragma unroll 8
      for (int k4 = 0; k4 < 32; ++k4) {
        float4 av = att4[k4];
        acc  += av.x * kc[(size_t)(4 * k4 + 0) * 512];
        acc  += av.y * kc[(size_t)(4 * k4 + 1) * 512];
        acc2 += av.z * kc[(size_t)(4 * k4 + 2) * 512];
        acc2 += av.w * kc[(size_t)(4 * k4 + 3) * 512];
      }
      const float lraw = (acc + acc2) / 11.313708498984761f;  // / sqrt(128)
      lg = tanhf(lraw) * 10.0f + emask;
      l_lds[t] = lg;
      unsigned x0 = 0u, x1 = (unsigned)(b * 512 + t);
      const uint2 kk = keys[i];
      threefry2x32(kk.x, kk.y, x0, x1);
      const unsigned bits = x0 ^ x1;
      float f = __uint_as_float((bits >> 9) | 0x3f800000u) - 1.0f;
      f = f + TINYF;
      f = fmaxf(TINYF, f);
      zv = lg + (-logf(-logf(f)));
    }
    {
      float z = zv; int zi = t;
      float mm = lg;
      for (int o = 32; o; o >>= 1) {
        float oz = __shfl_xor(z, o); int oi = __shfl_xor(zi, o);
        if (oz > z || (oz == z && oi < zi)) { z = oz; zi = oi; }
        mm = fmaxf(mm, __shfl_xor(mm, o));
      }
      float e = expf(lg - mm);             // NaN if wave fully masked (guarded)
      for (int o = 32; o; o >>= 1) e += __shfl_xor(e, o);
      if (l == 0) { redZ[w] = z; redI[w] = zi; redM[w] = mm; redD[w] = e; }
    }
    __syncthreads();                                   // barrier 2
    // ---- every thread combines the 8 wave records (uniform result)
    float bz = redZ[0]; int a = redI[0]; float M = redM[0];
#pragma unroll
    for (int ww = 1; ww < 8; ++ww) {
      float oz = redZ[ww]; int oi = redI[ww];
      if (oz > bz || (oz == bz && oi < a)) { bz = oz; a = oi; }
      M = fmaxf(M, redM[ww]);
    }
    if (t == 0) {
      float den = 0.0f;
#pragma unroll
      for (int ww = 0; ww < 8; ++ww) {
        float mw = redM[ww];
        if (mw != NEGINF) den += redD[ww] * expf(mw - M);
      }
      out_probs[i * 64 + b] = expf(l_lds[a] - M) / den;
      out_act[i * 64 + b] = (float)a;
    }
    ap = a;
    if (i == 0) af = a;
    const int n0 = l << 2;
    mk0.x = (a == n0)       ? NEGINF : mk0.x;
    mk0.y = (a == n0 + 1)   ? NEGINF : mk0.y;
    mk0.z = (a == n0 + 2)   ? NEGINF : mk0.z;
    mk0.w = (a == n0 + 3)   ? NEGINF : mk0.w;
    mk1.x = (a == 256 + n0)     ? NEGINF : mk1.x;
    mk1.y = (a == 256 + n0 + 1) ? NEGINF : mk1.y;
    mk1.z = (a == 256 + n0 + 2) ? NEGINF : mk1.z;
    mk1.w = (a == 256 + n0 + 3) ? NEGINF : mk1.w;
    emask = (a == t) ? NEGINF : emask;
  }
}

// ===========================================================================
extern "C" void kernel_launch(void* const* d_in, const int* in_sizes, int n_in,
                              void* d_out, int out_size, void* d_ws, size_t ws_size,
                              hipStream_t stream) {
  const float* problems = (const float*)d_in[0];
  const float* embed_W  = (const float*)d_in[1];
  const float* embed_b  = (const float*)d_in[2];
  const float* enc_Wq   = (const float*)d_in[3];
  const float* enc_Wk   = (const float*)d_in[4];
  const float* enc_Wv   = (const float*)d_in[5];
  const float* enc_Wo   = (const float*)d_in[6];
  const float* ln1g     = (const float*)d_in[7];
  const float* ln1b     = (const float*)d_in[8];
  const float* ffW1     = (const float*)d_in[9];
  const float* ffb1     = (const float*)d_in[10];
  const float* ffW2     = (const float*)d_in[11];
  const float* ffb2     = (const float*)d_in[12];
  const float* ln2g     = (const float*)d_in[13];
  const float* ln2b     = (const float*)d_in[14];
  const float* graph_W  = (const float*)d_in[15];
  const float* node_W   = (const float*)d_in[16];
  const float* dec_Wq   = (const float*)d_in[17];
  const float* dec_Wk   = (const float*)d_in[18];
  const float* dec_Wv   = (const float*)d_in[19];
  const float* dec_Wo   = (const float*)d_in[20];
  const float* W_v_f    = (const float*)d_in[21];
  const float* W_v_l    = (const float*)d_in[22];

  float* ws = (float*)d_ws;
  const size_t SZ = (size_t)64 * 512 * 128;      // 16 MB each
  float* X  = ws;
  float* Y  = ws + SZ;
  float* Qb = ws + 2 * SZ;
  float* Kb = ws + 3 * SZ;
  float* Vb = ws + 4 * SZ;
  float* NM = ws + 5 * SZ;
  float* GC = NM + 64 * 128;

  float* QG  = Y;
  float* QL  = Y + 8192;
  float* QF  = Y + 8192 + 65536;
  float* QL0 = Y + 8192 + 131072;
  float* QF0 = QL0 + 128;

  float* out       = (float*)d_out;
  float* out_probs = out;
  float* out_act   = out + 512 * 64;

  k_embed<<<16384, 256, 0, stream>>>(problems, embed_W, embed_b, X);

  for (int i = 0; i < 3; ++i) {
    const float* Wqi = enc_Wq + (size_t)i * 16384;
    const float* Wki = enc_Wk + (size_t)i * 16384;
    const float* Wvi = enc_Wv + (size_t)i * 16384;
    const float* Woi = enc_Wo + (size_t)i * 16384;
    k_gemm64_qkv<<<dim3(512, 2, 3), 256, 0, stream>>>(X, Wqi, Wki, Wvi, Qb, Kb, Vb);
    k_attn_enc<<<512, 512, 0, stream>>>(Qb, Kb, Vb, Y);
    k_gemm64<<<dim3(512, 2), 256, 0, stream>>>(Y, 128, Woi, 128, nullptr, X, Qb, 128, 128, GEP_ADDR);
    k_ln<<<8192, 256, 0, stream>>>(Qb, ln1g + i * 128, ln1b + i * 128, X, 32768);
    float* H = Kb;
    for (int half = 0; half < 2; ++half) {
      k_gemm64<<<dim3(512, 4), 256, 0, stream>>>(
          X, 128, ffW1 + (size_t)i * 65536 + half * 256, 512,
          ffb1 + i * 512 + half * 256, nullptr, H, 256, 128, GEP_BIAS | GEP_RELU);
      k_gemm64<<<dim3(512, 2), 256, 0, stream>>>(
          H, 256, ffW2 + (size_t)i * 65536 + (size_t)half * 32768, 128,
          ffb2 + i * 128, X, Y, 128, 256,
          half == 0 ? (GEP_BIAS | GEP_ADDR) : GEP_ACC);
    }
    k_ln<<<8192, 256, 0, stream>>>(Y, ln2g + i * 128, ln2b + i * 128, X, 32768);
  }

  k_mean<<<64, 128, 0, stream>>>(X, NM);
  k_gemm128<<<dim3(4, 8), 256, 0, stream>>>(NM, graph_W, nullptr, GC, 64);
  k_gemm128<<<dim3(4, 8), 256, 0, stream>>>(GC, dec_Wq, nullptr, QG, 64);
  k_gemm64<<<dim3(8, 2), 256, 0, stream>>>(X, 128, dec_Wq + 16384, 128, nullptr, nullptr, QL, 128, 128, 0);
  k_gemm64<<<dim3(8, 2), 256, 0, stream>>>(X, 128, dec_Wq + 32768, 128, nullptr, nullptr, QF, 128, 128, 0);
  k_gemm128<<<dim3(1, 8), 256, 0, stream>>>(W_v_l, dec_Wq + 16384, nullptr, QL0, 1);
  k_gemm128<<<dim3(1, 8), 256, 0, stream>>>(W_v_f, dec_Wq + 32768, nullptr, QF0, 1);
  k_gemm64<<<dim3(512, 2), 256, 0, stream>>>(X, 128, dec_Wk, 128, nullptr, nullptr, Qb, 128, 128, GEP_TST);   // Kt
  k_gemm64<<<dim3(512, 2), 256, 0, stream>>>(X, 128, dec_Wv, 128, nullptr, nullptr, Kb, 128, 128, GEP_TST);   // Vt
  k_gemm64<<<dim3(512, 2), 256, 0, stream>>>(X, 128, node_W, 128, nullptr, nullptr, Vb, 128, 128, 0);         // kn
  k_gemm64<<<dim3(512, 2), 256, 0, stream>>>(Vb, 128, dec_Wo, 128, nullptr, nullptr, X, 128, 128,
                                             GEP_WT | GEP_TST);                                               // KnWT

  k_decoder<<<64, 512, 0, stream>>>(Qb, Kb, X, QG, QL, QF, QL0, QF0,
                                    out_probs, out_act);
}